// Round 2
// baseline (384.259 us; speedup 1.0000x reference)
//
#include <hip/hip_runtime.h>
#include <hip/hip_fp16.h>

typedef _Float16 half4v __attribute__((ext_vector_type(4)));
typedef _Float16 half8v __attribute__((ext_vector_type(8)));
typedef float floatx4 __attribute__((ext_vector_type(4)));

// ---------------- convert f32 -> f16 (n multiple of 4) ----------------
__global__ __launch_bounds__(256) void k_f32_to_f16(const float* __restrict__ in,
                                                    _Float16* __restrict__ out, int n) {
    int i = (blockIdx.x * 256 + threadIdx.x) * 4;
    if (i >= n) return;
    float4 v = *(const float4*)(in + i);
    half4v h;
    h[0] = (_Float16)v.x; h[1] = (_Float16)v.y; h[2] = (_Float16)v.z; h[3] = (_Float16)v.w;
    *(half4v*)(out + i) = h;
}

// ------------- transpose + convert: in[R][C] f32 -> out[C][R] f16 -------------
__global__ __launch_bounds__(256) void k_transpose_f16(const float* __restrict__ in,
                                                       _Float16* __restrict__ out,
                                                       int R, int C) {
    __shared__ float tile[32][33];
    int bc = blockIdx.x * 32;
    int br = blockIdx.y * 32;
    int tx = threadIdx.x & 31, ty = threadIdx.x >> 5;  // 32x8
#pragma unroll
    for (int i = 0; i < 32; i += 8)
        tile[ty + i][tx] = in[(size_t)(br + ty + i) * C + bc + tx];
    __syncthreads();
#pragma unroll
    for (int i = 0; i < 32; i += 8)
        out[(size_t)(bc + ty + i) * R + br + tx] = (_Float16)tile[tx][ty + i];
}

// ---------------- NT GEMM: C[M,N] = scale * A[M,K] @ B[N,K]^T ----------------
// 128x128 tile, BK=64, 256 threads = 4 waves (2x2 of 64x64), mfma_f32_16x16x32_f16.
// LDS rows padded to 72 halves (144 B = 9x16 B -> b128 ops stay 16B-aligned).
// Staging: tile = 128 rows x 64 halves = 1024 x 16B chunks; each thread stages
// 4 chunks per matrix (sr = tid>>3 covers rows mod 32, sc = (tid&7)*8 covers the
// full 64-half row; rr walks +32). 8 consecutive threads = one contiguous 128 B
// global row -> coalesced dwordx4.
// OUT_F16: store f16. else: atomicAdd fp32 (split-K via blockIdx.z * kChunk).
template <bool OUT_F16>
__global__ __launch_bounds__(256) void k_gemm_nt(const _Float16* __restrict__ A,
                                                 const _Float16* __restrict__ B,
                                                 void* __restrict__ C,
                                                 int M, int N, int K, int kChunk,
                                                 float scale) {
    __shared__ _Float16 As[128 * 72];
    __shared__ _Float16 Bs[128 * 72];
    const int tid  = threadIdx.x;
    const int lane = tid & 63;
    const int wave = tid >> 6;
    const int wm   = (wave >> 1) * 64;
    const int wn   = (wave & 1) * 64;
    const int quad = lane >> 4;
    const int lr   = lane & 15;
    const long m0 = (long)blockIdx.y * 128;
    const long n0 = (long)blockIdx.x * 128;
    const int kBegin = blockIdx.z * kChunk;
    const int kEnd   = kBegin + kChunk;

    floatx4 acc[4][4] = {};

    const int sr = tid >> 3;        // 0..31
    const int sc = (tid & 7) * 8;   // half-offset 0..56

    for (int kt = kBegin; kt < kEnd; kt += 64) {
        const _Float16* Ap = A + (m0 + sr) * (long)K + kt + sc;
        const _Float16* Bp = B + (n0 + sr) * (long)K + kt + sc;
        uint4 av[4], bv[4];
#pragma unroll
        for (int r = 0; r < 4; ++r) {
            av[r] = *(const uint4*)(Ap + (long)(r * 32) * K);
            bv[r] = *(const uint4*)(Bp + (long)(r * 32) * K);
        }
#pragma unroll
        for (int r = 0; r < 4; ++r) {
            *(uint4*)&As[(sr + r * 32) * 72 + sc] = av[r];
            *(uint4*)&Bs[(sr + r * 32) * 72 + sc] = bv[r];
        }
        __syncthreads();

#pragma unroll
        for (int kk = 0; kk < 64; kk += 32) {
            half8v af[4], bf[4];
#pragma unroll
            for (int i = 0; i < 4; ++i)
                af[i] = *(const half8v*)&As[(wm + i * 16 + lr) * 72 + kk + quad * 8];
#pragma unroll
            for (int j = 0; j < 4; ++j)
                bf[j] = *(const half8v*)&Bs[(wn + j * 16 + lr) * 72 + kk + quad * 8];
#pragma unroll
            for (int i = 0; i < 4; ++i)
#pragma unroll
                for (int j = 0; j < 4; ++j)
                    acc[i][j] = __builtin_amdgcn_mfma_f32_16x16x32_f16(af[i], bf[j], acc[i][j], 0, 0, 0);
        }
        __syncthreads();
    }

    // epilogue: C/D layout col = lane&15, row = quad*4 + reg  [m89/m91]
#pragma unroll
    for (int i = 0; i < 4; ++i) {
        long rbase = m0 + wm + i * 16 + quad * 4;
#pragma unroll
        for (int j = 0; j < 4; ++j) {
            long col = n0 + wn + j * 16 + lr;
#pragma unroll
            for (int r = 0; r < 4; ++r) {
                float val = acc[i][j][r] * scale;
                if (OUT_F16)
                    ((_Float16*)C)[(rbase + r) * (long)N + col] = (_Float16)val;
                else
                    atomicAdd((float*)C + (rbase + r) * (long)N + col, val);
            }
        }
    }
}

// ---------------- masked softmax, in-place on f16 logits [Q=4096][N=8192] ----------------
__global__ __launch_bounds__(256) void k_softmax(_Float16* __restrict__ logits,
                                                 const int* __restrict__ mask) {
    const int q   = blockIdx.x;
    const int tid = threadIdx.x;
    _Float16* row   = logits + (size_t)q * 8192;
    const int* mrow = mask + (size_t)q * 8192;

    float v[32];
    unsigned mb = 0;
    float lmax = -3.0e38f;
#pragma unroll
    for (int i = 0; i < 8; ++i) {
        int base = i * 1024 + tid * 4;
        int4 mm  = *(const int4*)(mrow + base);
        half4v h = *(const half4v*)(row + base);
#pragma unroll
        for (int j = 0; j < 4; ++j) v[i * 4 + j] = (float)h[j];
        if (mm.x > 0) { mb |= 1u << (i * 4 + 0); lmax = fmaxf(lmax, v[i * 4 + 0]); }
        if (mm.y > 0) { mb |= 1u << (i * 4 + 1); lmax = fmaxf(lmax, v[i * 4 + 1]); }
        if (mm.z > 0) { mb |= 1u << (i * 4 + 2); lmax = fmaxf(lmax, v[i * 4 + 2]); }
        if (mm.w > 0) { mb |= 1u << (i * 4 + 3); lmax = fmaxf(lmax, v[i * 4 + 3]); }
    }
#pragma unroll
    for (int off = 32; off > 0; off >>= 1) lmax = fmaxf(lmax, __shfl_xor(lmax, off, 64));
    __shared__ float redmax[4], redsum[4];
    if ((tid & 63) == 0) redmax[tid >> 6] = lmax;
    __syncthreads();
    lmax = fmaxf(fmaxf(redmax[0], redmax[1]), fmaxf(redmax[2], redmax[3]));

    float lsum = 0.f;
#pragma unroll
    for (int i = 0; i < 32; ++i) {
        float e = ((mb >> i) & 1u) ? __expf(v[i] - lmax) : 0.f;
        v[i] = e;
        lsum += e;
    }
#pragma unroll
    for (int off = 32; off > 0; off >>= 1) lsum += __shfl_xor(lsum, off, 64);
    if ((tid & 63) == 0) redsum[tid >> 6] = lsum;
    __syncthreads();
    lsum = redsum[0] + redsum[1] + redsum[2] + redsum[3];
    float inv = lsum > 0.f ? 1.f / lsum : 0.f;

#pragma unroll
    for (int i = 0; i < 8; ++i) {
        int base = i * 1024 + tid * 4;
        half4v h;
#pragma unroll
        for (int j = 0; j < 4; ++j) h[j] = (_Float16)(v[i * 4 + j] * inv);
        *(half4v*)(row + base) = h;
    }
}

extern "C" void kernel_launch(void* const* d_in, const int* in_sizes, int n_in,
                              void* d_out, int out_size, void* d_ws, size_t ws_size,
                              hipStream_t stream) {
    const float* search_x = (const float*)d_in[0];  // [8192,1024]
    const float* search_y = (const float*)d_in[1];  // [8192,256]
    const float* query_x  = (const float*)d_in[2];  // [4096,1024]
    const int*   mask     = (const int*)d_in[3];    // [4096,8192]
    const float* Wk       = (const float*)d_in[4];  // [1024,512]
    const float* Wq       = (const float*)d_in[5];  // [1024,512]
    (void)in_sizes; (void)n_in; (void)ws_size;

    char* p = (char*)d_ws;
    _Float16* xh   = (_Float16*)p; p += (size_t)8192 * 1024 * 2;  // x f16
    _Float16* qh   = (_Float16*)p; p += (size_t)4096 * 1024 * 2;  // q f16
    _Float16* wkT  = (_Float16*)p; p += (size_t)512 * 1024 * 2;   // Wk^T f16 [512,1024]
    _Float16* wqT  = (_Float16*)p; p += (size_t)512 * 1024 * 2;   // Wq^T f16
    _Float16* yT   = (_Float16*)p; p += (size_t)256 * 8192 * 2;   // y^T f16 [256,8192]
    _Float16* keys = (_Float16*)p; p += (size_t)8192 * 512 * 2;   // keys f16 [8192,512]
    _Float16* qk   = (_Float16*)p; p += (size_t)4096 * 512 * 2;   // qk f16 [4096,512]
    _Float16* lg   = (_Float16*)p; p += (size_t)4096 * 8192 * 2;  // logits/p f16

    // converts + transposes
    k_f32_to_f16<<<8192, 256, 0, stream>>>(search_x, xh, 8192 * 1024);
    k_f32_to_f16<<<4096, 256, 0, stream>>>(query_x, qh, 4096 * 1024);
    k_transpose_f16<<<dim3(16, 32), 256, 0, stream>>>(Wk, wkT, 1024, 512);
    k_transpose_f16<<<dim3(16, 32), 256, 0, stream>>>(Wq, wqT, 1024, 512);
    k_transpose_f16<<<dim3(8, 256), 256, 0, stream>>>(search_y, yT, 8192, 256);

    // keys = x @ Wk   (M=8192,N=512,K=1024)
    k_gemm_nt<true><<<dim3(4, 64, 1), 256, 0, stream>>>(xh, wkT, keys, 8192, 512, 1024, 1024, 1.0f);
    // qk = q @ Wq     (M=4096,N=512,K=1024)
    k_gemm_nt<true><<<dim3(4, 32, 1), 256, 0, stream>>>(qh, wqT, qk, 4096, 512, 1024, 1024, 1.0f);
    // logits = (qk @ keys^T) / sqrt(512)   (M=4096,N=8192,K=512)
    k_gemm_nt<true><<<dim3(64, 32, 1), 256, 0, stream>>>(qk, keys, lg, 4096, 8192, 512, 512,
                                                         0.04419417382415922f);
    // masked softmax in-place
    k_softmax<<<4096, 256, 0, stream>>>(lg, mask);
    // out = p @ y     (M=4096,N=256,K=8192), split-K=8 with fp32 atomics
    hipMemsetAsync(d_out, 0, (size_t)out_size * sizeof(float), stream);
    k_gemm_nt<false><<<dim3(2, 32, 8), 256, 0, stream>>>(lg, yT, (float*)d_out, 4096, 256, 8192,
                                                         1024, 1.0f);
}

// Round 3
// 367.143 us; speedup vs baseline: 1.0466x; 1.0466x over previous
//
#include <hip/hip_runtime.h>
#include <hip/hip_fp16.h>

typedef _Float16 half4v __attribute__((ext_vector_type(4)));
typedef _Float16 half8v __attribute__((ext_vector_type(8)));
typedef float floatx4 __attribute__((ext_vector_type(4)));

#define GLOBAL_AS __attribute__((address_space(1)))
#define LDS_AS __attribute__((address_space(3)))

// async 16B/lane global->LDS DMA; lds dest = wave-uniform base + lane*16
__device__ __forceinline__ void async_copy16(const _Float16* g, _Float16* l) {
    __builtin_amdgcn_global_load_lds((const GLOBAL_AS unsigned int*)g,
                                     (LDS_AS unsigned int*)l, 16, 0, 0);
}

// ---------------- convert f32 -> f16 (n multiple of 4) ----------------
__global__ __launch_bounds__(256) void k_f32_to_f16(const float* __restrict__ in,
                                                    _Float16* __restrict__ out, int n) {
    int i = (blockIdx.x * 256 + threadIdx.x) * 4;
    if (i >= n) return;
    float4 v = *(const float4*)(in + i);
    half4v h;
    h[0] = (_Float16)v.x; h[1] = (_Float16)v.y; h[2] = (_Float16)v.z; h[3] = (_Float16)v.w;
    *(half4v*)(out + i) = h;
}

// ------------- transpose + convert: in[R][C] f32 -> out[C][R] f16 -------------
__global__ __launch_bounds__(256) void k_transpose_f16(const float* __restrict__ in,
                                                       _Float16* __restrict__ out,
                                                       int R, int C) {
    __shared__ float tile[32][33];
    int bc = blockIdx.x * 32;
    int br = blockIdx.y * 32;
    int tx = threadIdx.x & 31, ty = threadIdx.x >> 5;  // 32x8
#pragma unroll
    for (int i = 0; i < 32; i += 8)
        tile[ty + i][tx] = in[(size_t)(br + ty + i) * C + bc + tx];
    __syncthreads();
#pragma unroll
    for (int i = 0; i < 32; i += 8)
        out[(size_t)(bc + ty + i) * R + br + tx] = (_Float16)tile[tx][ty + i];
}

// ---------------- NT GEMM: C[M,N] = scale * A[M,K] @ B[N,K]^T ----------------
// 128x128 tile, BK=64, 256 threads = 4 waves (2x2 of 64x64), mfma_f32_16x16x32_f16.
// Staging: global_load_lds width=16 (m97 ladder step). LDS tile is UNPADDED
// row-major (row stride 64 halves = 128 B) as required by the wave-uniform-base
// +lane*16 DMA. Bank conflicts on fragment reads are killed by an XOR chunk
// swizzle: LDS slot (row, c) holds global 16B-chunk (row, c ^ (row&7)).
// Stager: lane covers row offset rl=lane>>3, slot chunk lane&7, so the global
// chunk it must fetch is (lane&7)^(lane>>3) -- i-independent.
// Fragment read of global chunk cg at row ra reads slot (ra, cg ^ (ra&7));
// banks = ((cg^(lr&7))*4)%32 -> full 32-bank spread, 2-way max (free, m136).
// OUT_MODE 0: f16 store. OUT_MODE 1: fp32 partial store at C + blockIdx.z*M*N
// (split-K partials; reduced by k_reduce8 -- no atomics).
template <int OUT_MODE>
__global__ __launch_bounds__(256) void k_gemm_nt(const _Float16* __restrict__ A,
                                                 const _Float16* __restrict__ B,
                                                 void* __restrict__ C,
                                                 int M, int N, int K, int kChunk,
                                                 float scale) {
    __shared__ __align__(16) _Float16 As[128 * 64];
    __shared__ __align__(16) _Float16 Bs[128 * 64];
    const int tid  = threadIdx.x;
    const int lane = tid & 63;
    const int wave = tid >> 6;
    const int wm   = (wave >> 1) * 64;
    const int wn   = (wave & 1) * 64;
    const int quad = lane >> 4;
    const int lr   = lane & 15;
    const long m0 = (long)blockIdx.y * 128;
    const long n0 = (long)blockIdx.x * 128;
    const int kBegin = blockIdx.z * kChunk;
    const int kEnd   = kBegin + kChunk;

    floatx4 acc[4][4] = {};

    // stager geometry (per lane, i-independent)
    const int rl = lane >> 3;                       // row offset within 8-row group
    const int gc = (lane & 7) ^ rl;                 // swizzled global chunk
    const long arow = m0 + wave * 32 + rl;          // + i*8
    const long brow = n0 + wave * 32 + rl;

    for (int kt = kBegin; kt < kEnd; kt += 64) {
        const _Float16* Ap = A + arow * (long)K + kt + gc * 8;
        const _Float16* Bp = B + brow * (long)K + kt + gc * 8;
        _Float16* Al = &As[(wave * 32) * 64];
        _Float16* Bl = &Bs[(wave * 32) * 64];
#pragma unroll
        for (int i = 0; i < 4; ++i) {
            async_copy16(Ap + (long)(i * 8) * K, Al + i * 8 * 64);
            async_copy16(Bp + (long)(i * 8) * K, Bl + i * 8 * 64);
        }
        __syncthreads();  // compiler inserts vmcnt(0) drain before barrier

#pragma unroll
        for (int kk = 0; kk < 64; kk += 32) {
            half8v af[4], bf[4];
            const int cg = (kk >> 3) + quad;        // global chunk index 0..7
            const int sl = (cg ^ (lr & 7)) * 8;     // swizzled slot offset (halves)
#pragma unroll
            for (int i = 0; i < 4; ++i)
                af[i] = *(const half8v*)&As[(wm + i * 16 + lr) * 64 + sl];
#pragma unroll
            for (int j = 0; j < 4; ++j)
                bf[j] = *(const half8v*)&Bs[(wn + j * 16 + lr) * 64 + sl];
#pragma unroll
            for (int i = 0; i < 4; ++i)
#pragma unroll
                for (int j = 0; j < 4; ++j)
                    acc[i][j] = __builtin_amdgcn_mfma_f32_16x16x32_f16(af[i], bf[j], acc[i][j], 0, 0, 0);
        }
        __syncthreads();
    }

    // epilogue: C/D layout col = lane&15, row = quad*4 + reg  [m89/m91]
#pragma unroll
    for (int i = 0; i < 4; ++i) {
        long rbase = m0 + wm + i * 16 + quad * 4;
#pragma unroll
        for (int j = 0; j < 4; ++j) {
            long col = n0 + wn + j * 16 + lr;
#pragma unroll
            for (int r = 0; r < 4; ++r) {
                float val = acc[i][j][r] * scale;
                if (OUT_MODE == 0)
                    ((_Float16*)C)[(rbase + r) * (long)N + col] = (_Float16)val;
                else
                    ((float*)C)[(size_t)blockIdx.z * M * N + (rbase + r) * (long)N + col] = val;
            }
        }
    }
}

// ---------------- sum 8 fp32 partials [8][n] -> out[n] (n multiple of 4) ----------------
__global__ __launch_bounds__(256) void k_reduce8(const float* __restrict__ part,
                                                 float* __restrict__ out, int n) {
    int i = (blockIdx.x * 256 + threadIdx.x) * 4;
    if (i >= n) return;
    float4 s = *(const float4*)(part + i);
#pragma unroll
    for (int z = 1; z < 8; ++z) {
        float4 v = *(const float4*)(part + (size_t)z * n + i);
        s.x += v.x; s.y += v.y; s.z += v.z; s.w += v.w;
    }
    *(float4*)(out + i) = s;
}

// ---------------- masked softmax, in-place on f16 logits [Q=4096][N=8192] ----------------
__global__ __launch_bounds__(256) void k_softmax(_Float16* __restrict__ logits,
                                                 const int* __restrict__ mask) {
    const int q   = blockIdx.x;
    const int tid = threadIdx.x;
    _Float16* row   = logits + (size_t)q * 8192;
    const int* mrow = mask + (size_t)q * 8192;

    float v[32];
    unsigned mb = 0;
    float lmax = -3.0e38f;
#pragma unroll
    for (int i = 0; i < 8; ++i) {
        int base = i * 1024 + tid * 4;
        int4 mm  = *(const int4*)(mrow + base);
        half4v h = *(const half4v*)(row + base);
#pragma unroll
        for (int j = 0; j < 4; ++j) v[i * 4 + j] = (float)h[j];
        if (mm.x > 0) { mb |= 1u << (i * 4 + 0); lmax = fmaxf(lmax, v[i * 4 + 0]); }
        if (mm.y > 0) { mb |= 1u << (i * 4 + 1); lmax = fmaxf(lmax, v[i * 4 + 1]); }
        if (mm.z > 0) { mb |= 1u << (i * 4 + 2); lmax = fmaxf(lmax, v[i * 4 + 2]); }
        if (mm.w > 0) { mb |= 1u << (i * 4 + 3); lmax = fmaxf(lmax, v[i * 4 + 3]); }
    }
#pragma unroll
    for (int off = 32; off > 0; off >>= 1) lmax = fmaxf(lmax, __shfl_xor(lmax, off, 64));
    __shared__ float redmax[4], redsum[4];
    if ((tid & 63) == 0) redmax[tid >> 6] = lmax;
    __syncthreads();
    lmax = fmaxf(fmaxf(redmax[0], redmax[1]), fmaxf(redmax[2], redmax[3]));

    float lsum = 0.f;
#pragma unroll
    for (int i = 0; i < 32; ++i) {
        float e = ((mb >> i) & 1u) ? __expf(v[i] - lmax) : 0.f;
        v[i] = e;
        lsum += e;
    }
#pragma unroll
    for (int off = 32; off > 0; off >>= 1) lsum += __shfl_xor(lsum, off, 64);
    if ((tid & 63) == 0) redsum[tid >> 6] = lsum;
    __syncthreads();
    lsum = redsum[0] + redsum[1] + redsum[2] + redsum[3];
    float inv = lsum > 0.f ? 1.f / lsum : 0.f;

#pragma unroll
    for (int i = 0; i < 8; ++i) {
        int base = i * 1024 + tid * 4;
        half4v h;
#pragma unroll
        for (int j = 0; j < 4; ++j) h[j] = (_Float16)(v[i * 4 + j] * inv);
        *(half4v*)(row + base) = h;
    }
}

extern "C" void kernel_launch(void* const* d_in, const int* in_sizes, int n_in,
                              void* d_out, int out_size, void* d_ws, size_t ws_size,
                              hipStream_t stream) {
    const float* search_x = (const float*)d_in[0];  // [8192,1024]
    const float* search_y = (const float*)d_in[1];  // [8192,256]
    const float* query_x  = (const float*)d_in[2];  // [4096,1024]
    const int*   mask     = (const int*)d_in[3];    // [4096,8192]
    const float* Wk       = (const float*)d_in[4];  // [1024,512]
    const float* Wq       = (const float*)d_in[5];  // [1024,512]
    (void)in_sizes; (void)n_in; (void)ws_size; (void)out_size;

    char* p = (char*)d_ws;
    _Float16* xh   = (_Float16*)p; p += (size_t)8192 * 1024 * 2;  // x f16
    _Float16* qh   = (_Float16*)p; p += (size_t)4096 * 1024 * 2;  // q f16
    _Float16* wkT  = (_Float16*)p; p += (size_t)512 * 1024 * 2;   // Wk^T f16 [512,1024]
    _Float16* wqT  = (_Float16*)p; p += (size_t)512 * 1024 * 2;   // Wq^T f16
    _Float16* yT   = (_Float16*)p; p += (size_t)256 * 8192 * 2;   // y^T f16 [256,8192]
    _Float16* keys = (_Float16*)p; p += (size_t)8192 * 512 * 2;   // keys f16 [8192,512]
    _Float16* qk   = (_Float16*)p; p += (size_t)4096 * 512 * 2;   // qk f16 [4096,512]
    _Float16* lg   = (_Float16*)p; p += (size_t)4096 * 8192 * 2;  // logits/p f16
    float*    part = (float*)p;    p += (size_t)8 * 4096 * 256 * 4; // PV split-K partials

    // converts + transposes
    k_f32_to_f16<<<8192, 256, 0, stream>>>(search_x, xh, 8192 * 1024);
    k_f32_to_f16<<<4096, 256, 0, stream>>>(query_x, qh, 4096 * 1024);
    k_transpose_f16<<<dim3(16, 32), 256, 0, stream>>>(Wk, wkT, 1024, 512);
    k_transpose_f16<<<dim3(16, 32), 256, 0, stream>>>(Wq, wqT, 1024, 512);
    k_transpose_f16<<<dim3(8, 256), 256, 0, stream>>>(search_y, yT, 8192, 256);

    // keys = x @ Wk   (M=8192,N=512,K=1024)
    k_gemm_nt<0><<<dim3(4, 64, 1), 256, 0, stream>>>(xh, wkT, keys, 8192, 512, 1024, 1024, 1.0f);
    // qk = q @ Wq     (M=4096,N=512,K=1024)
    k_gemm_nt<0><<<dim3(4, 32, 1), 256, 0, stream>>>(qh, wqT, qk, 4096, 512, 1024, 1024, 1.0f);
    // logits = (qk @ keys^T) / sqrt(512)   (M=4096,N=8192,K=512)
    k_gemm_nt<0><<<dim3(64, 32, 1), 256, 0, stream>>>(qk, keys, lg, 4096, 8192, 512, 512,
                                                      0.04419417382415922f);
    // masked softmax in-place
    k_softmax<<<4096, 256, 0, stream>>>(lg, mask);
    // out = p @ y     (M=4096,N=256,K=8192), split-K=8 -> fp32 partials, then reduce
    k_gemm_nt<1><<<dim3(2, 32, 8), 256, 0, stream>>>(lg, yT, part, 4096, 256, 8192, 1024, 1.0f);
    k_reduce8<<<1024, 256, 0, stream>>>(part, (float*)d_out, 4096 * 256);
}